// Round 7
// baseline (271.080 us; speedup 1.0000x reference)
//
#include <hip/hip_runtime.h>
#include <hip/hip_bf16.h>

// ---------------------------------------------------------------------------
// HAttention1D: B=4 N=4096 DIM=1024 HEADS=8 DH=64 BSZ=16, 8 levels (0..7)
//  1) f2b3: x, w_qkv, w_out -> bf16 (single launch, 8 elems/thread)
//  2) gemm_qkv (128x128 MFMA, 2 dispatches for profiler visibility):
//     qkv = x@w_qkv^T; epilogue scatters level-0 + emits level-4 rows
//  3) coarse47 (per bh, 512 thr): levels 4..7 attn+pyramid in LDS
//  4) fused03 (per (bh, 256-row chunk), 512 thr): levels 0..3 attn+pyramid
//     + final combine -> Ub
//  LDS swizzle: f(r) = (r^(r>>3))&7 (full spread at strided coarse levels);
//  vT transpose buffer has per-q 16-short pad (kills 8-way write conflict).
//  5) gemm_out (128x128 MFMA): out = U @ w_out^T + b_out
// ---------------------------------------------------------------------------

typedef __bf16 bf16x8 __attribute__((ext_vector_type(8)));
typedef float floatx4 __attribute__((ext_vector_type(4)));
typedef unsigned short ushortx8 __attribute__((ext_vector_type(8)));
typedef unsigned int uintx4 __attribute__((ext_vector_type(4)));

#define ROWS_PER_BH 8160  // 4096+2048+1024+512+256+128+64+32

__device__ __forceinline__ void g2lds16(const void* g, void* l) {
  __builtin_amdgcn_global_load_lds(
      (const __attribute__((address_space(1))) void*)g,
      (__attribute__((address_space(3))) void*)l, 16, 0, 0);
}

__device__ __forceinline__ unsigned short f2bu(float x) {
  __hip_bfloat16 h = __float2bfloat16(x);
  return *(unsigned short*)&h;
}
__device__ __forceinline__ float bu2f(unsigned short u) {
  __hip_bfloat16 h = *(__hip_bfloat16*)&u;
  return __bfloat162float(h);
}

// ---- fp32 -> bf16 convert, all three tensors, 8 elems/thread --------------
__global__ __launch_bounds__(256) void f2b3_kernel(const float* __restrict__ x,
                                                   const float* __restrict__ wq,
                                                   const float* __restrict__ wo,
                                                   __hip_bfloat16* __restrict__ xb,
                                                   __hip_bfloat16* __restrict__ wqb,
                                                   __hip_bfloat16* __restrict__ wob) {
  int i0 = (blockIdx.x * 256 + threadIdx.x) * 8;
  const float* s;
  __hip_bfloat16* d;
  if (i0 < 16777216) {
    s = x + i0; d = xb + i0;
  } else if (i0 < 16777216 + 1572864) {
    s = wq + (i0 - 16777216); d = wqb + (i0 - 16777216);
  } else {
    s = wo + (i0 - 16777216 - 1572864); d = wob + (i0 - 16777216 - 1572864);
  }
  float4 v0 = *(const float4*)s;
  float4 v1 = *(const float4*)(s + 4);
  ushortx8 o;
  o[0] = f2bu(v0.x); o[1] = f2bu(v0.y); o[2] = f2bu(v0.z); o[3] = f2bu(v0.w);
  o[4] = f2bu(v1.x); o[5] = f2bu(v1.y); o[6] = f2bu(v1.z); o[7] = f2bu(v1.w);
  *(ushortx8*)d = o;
}

// ---- shared GEMM core: 128x128 tile, BK=64, XOR-swizzled LDS --------------
template <int K>
__device__ __forceinline__ void gemm_core(const unsigned short* __restrict__ A,
                                          const unsigned short* __restrict__ B,
                                          unsigned short* ldsA, unsigned short* ldsB,
                                          int tM, int tN, floatx4 acc[4][4]) {
  const int tid = threadIdx.x;
  const int lane = tid & 63, w = tid >> 6;
  const int wm = w >> 1, wn = w & 1;
  const int lr = lane >> 3;            // row-within-8 for staging
  const int gch = (lane & 7) ^ lr;     // XOR-swizzled global chunk
  const unsigned short* Ag = A + (size_t)(tM + w * 32 + lr) * K + gch * 8;
  const unsigned short* Bg = B + (size_t)(tN + w * 32 + lr) * K + gch * 8;
  unsigned short* lA = &ldsA[w * 2048 + lane * 8];
  unsigned short* lB = &ldsB[w * 2048 + lane * 8];

  const int rA = wm * 64 + (lane & 15);
  const int rB = wn * 64 + (lane & 15);
  const int quad = lane >> 4;
  const int sw = lane & 7;             // fragment row & 7

  for (int kt = 0; kt < K; kt += 64) {
    __syncthreads();
#pragma unroll
    for (int c = 0; c < 4; c++) {
      g2lds16(Ag + (size_t)(c * 8) * K + kt, lA + c * 512);
      g2lds16(Bg + (size_t)(c * 8) * K + kt, lB + c * 512);
    }
    __syncthreads();
#pragma unroll
    for (int kk = 0; kk < 2; kk++) {
      bf16x8 af[4], bv[4];
#pragma unroll
      for (int i = 0; i < 4; i++)
        af[i] = *(const bf16x8*)&ldsA[(rA + i * 16) * 64 + (((kk * 4 + quad) ^ sw) * 8)];
#pragma unroll
      for (int j = 0; j < 4; j++)
        bv[j] = *(const bf16x8*)&ldsB[(rB + j * 16) * 64 + (((kk * 4 + quad) ^ sw) * 8)];
#pragma unroll
      for (int i = 0; i < 4; i++)
#pragma unroll
        for (int j = 0; j < 4; j++)
          acc[i][j] = __builtin_amdgcn_mfma_f32_16x16x32_bf16(af[i], bv[j], acc[i][j], 0, 0, 0);
    }
  }
}

// ---- GEMM1: qkv = x[16384,1024] @ w_qkv[1536,1024]^T ----------------------
// epilogue: scatter level-0 + emit level-4 rows (mean/mean/sum of 16 rows)
// tMoff splits the M range into two dispatches (profiler visibility).
__global__ __launch_bounds__(256) void gemm_qkv_kernel(
    const unsigned short* __restrict__ A,   // xb [16384,1024] bf16
    const unsigned short* __restrict__ B,   // wqkvb [1536,1024] bf16
    __hip_bfloat16* __restrict__ qp, __hip_bfloat16* __restrict__ kp,
    __hip_bfloat16* __restrict__ vp, int tMoff) {
  __shared__ unsigned short ldsA[128 * 64];
  __shared__ unsigned short ldsB[128 * 64];
  const int lane = threadIdx.x & 63, w = threadIdx.x >> 6;
  const int wm = w >> 1, wn = w & 1;
  const int tM = tMoff + blockIdx.x * 128, tN = blockIdx.y * 128;

  floatx4 acc[4][4];
#pragma unroll
  for (int i = 0; i < 4; i++)
#pragma unroll
    for (int j = 0; j < 4; j++) acc[i][j] = (floatx4){0.f, 0.f, 0.f, 0.f};

  gemm_core<1024>(A, B, ldsA, ldsB, tM, tN, acc);

  // epilogue: C/D layout col=lane&15, row=(lane>>4)*4+r  [verified m89]
  const int quad = lane >> 4, m15 = lane & 15;
#pragma unroll
  for (int i = 0; i < 4; i++) {
#pragma unroll
    for (int j = 0; j < 4; j++) {
      const int c = tN + wn * 64 + j * 16 + m15;
      const int tensor = c >> 9;         // 0=q 1=k 2=v
      const int rem = c & 511;
      const int h = rem >> 6, d = rem & 63;
      __hip_bfloat16* dstbuf = (tensor == 0) ? qp : ((tensor == 1) ? kp : vp);
      const float scale = (tensor == 0) ? 0.125f : 1.0f;  // DH^-0.5
#pragma unroll
      for (int r = 0; r < 4; r++) {
        const int m = tM + wm * 64 + i * 16 + quad * 4 + r;
        const int b = m >> 12, n = m & 4095;
        size_t dst = ((size_t)(b * 8 + h) * ROWS_PER_BH + n) * 64 + d;
        dstbuf[dst] = __float2bfloat16(acc[i][j][r] * scale);
      }
      // level-4 row: sum of 16 consecutive rows (in-lane 4 + cross-quad)
      float s4 = acc[i][j][0] + acc[i][j][1] + acc[i][j][2] + acc[i][j][3];
      s4 += __shfl_xor(s4, 16, 64);
      s4 += __shfl_xor(s4, 32, 64);
      if (quad == 0) {
        const int mrow = tM + wm * 64 + i * 16;     // multiple of 16
        const int b = mrow >> 12, n4 = (mrow & 4095) >> 4;
        // q: mean*0.125; k: mean; v: sum
        const float val = (tensor == 0) ? s4 * (0.125f / 16.f)
                         : ((tensor == 1) ? s4 * (1.f / 16.f) : s4);
        dstbuf[((size_t)(b * 8 + h) * ROWS_PER_BH + 7680 + n4) * 64 + d] =
            __float2bfloat16(val);
      }
    }
  }
}

// ---- GEMM2: out = U[16384,512] @ w_out[1024,512]^T + b_out ----------------
__global__ __launch_bounds__(256) void gemm_out_kernel(
    const unsigned short* __restrict__ A,   // Ub [16384,512] bf16
    const unsigned short* __restrict__ B,   // wob [1024,512] bf16
    const float* __restrict__ bias, float* __restrict__ out) {
  __shared__ unsigned short ldsA[128 * 64];
  __shared__ unsigned short ldsB[128 * 64];
  const int lane = threadIdx.x & 63, w = threadIdx.x >> 6;
  const int wm = w >> 1, wn = w & 1;
  const int tM = blockIdx.x * 128, tN = blockIdx.y * 128;

  floatx4 acc[4][4];
#pragma unroll
  for (int i = 0; i < 4; i++)
#pragma unroll
    for (int j = 0; j < 4; j++) acc[i][j] = (floatx4){0.f, 0.f, 0.f, 0.f};

  gemm_core<512>(A, B, ldsA, ldsB, tM, tN, acc);

  const int quad = lane >> 4;
#pragma unroll
  for (int i = 0; i < 4; i++) {
#pragma unroll
    for (int j = 0; j < 4; j++) {
      const int c = tN + wn * 64 + j * 16 + (lane & 15);
      const float bb = bias[c];
#pragma unroll
      for (int r = 0; r < 4; r++) {
        const int m = tM + wm * 64 + i * 16 + quad * 4 + r;
        out[(size_t)m * 1024 + c] = acc[i][j][r] + bb;
      }
    }
  }
}

// swizzle class: full 8-way spread even for rows strided by 2^l (l<=3)
__device__ __forceinline__ int swzf(int r) { return (r ^ (r >> 3)) & 7; }
// swizzled LDS index for [256][64] bf16 tile
__device__ __forceinline__ int sidx(int r, int d) {
  return r * 64 + (((d >> 3) ^ swzf(r)) << 3) + (d & 7);
}
// vT (transposed V) addressing: element (d, vrow) at (d>>4)*16 + d*24 + vrow
// (per-q 16-short pad spreads the 4 q-groups 8 banks apart on writes)
#define VT_SZ 1600

// ---- coarse47: per bh (512 thr): levels 4..7 attn+pyramid in LDS ----------
__global__ __launch_bounds__(512, 1) void coarse47_kernel(
    const unsigned short* __restrict__ qp, const unsigned short* __restrict__ kp,
    const unsigned short* __restrict__ vp, __hip_bfloat16* __restrict__ yall,
    float* __restrict__ aall) {
  __shared__ __align__(16) unsigned short qs[256 * 64];
  __shared__ __align__(16) unsigned short ks[256 * 64];
  __shared__ __align__(16) unsigned short vs[256 * 64];
  __shared__ __align__(16) unsigned short vT[8][VT_SZ];

  const int tid = threadIdx.x;
  const int w = tid >> 6, lane = tid & 63;
  const int m = lane & 15, q = lane >> 4;
  const int bh = blockIdx.x;
  const size_t base = (size_t)bh * ROWS_PER_BH;
  const size_t g0 = (base + 7680) * 64;

  unsigned short* vtw = vT[w];

  // stage (pre-swizzled global source, linear LDS dest): 4 issues/tensor
  {
    const int srow = tid >> 3;                    // 0..63
    const int sch = (tid & 7) ^ swzf(srow);       // row = it*64+srow, swzf same
    const size_t gofs = (size_t)srow * 64 + sch * 8;
#pragma unroll
    for (int it = 0; it < 4; it++) {
      const size_t gi = g0 + (size_t)it * 4096 + gofs;
      g2lds16(qp + gi, &qs[it * 4096 + tid * 8]);
      g2lds16(kp + gi, &ks[it * 4096 + tid * 8]);
      g2lds16(vp + gi, &vs[it * 4096 + tid * 8]);
    }
  }
  __syncthreads();

  auto attn_block = [&](int level, int blk, bool flip, floatx4 yout[4]) -> float {
    const int kb = flip ? (blk ^ 1) : blk;
    const int Rq = (blk * 16 + m) << level;
    const int Rk = (kb * 16 + m) << level;
    const bf16x8 ka0 = *(const bf16x8*)&ks[sidx(Rk, q * 8)];
    const bf16x8 ka1 = *(const bf16x8*)&ks[sidx(Rk, 32 + q * 8)];
    const bf16x8 qb0 = *(const bf16x8*)&qs[sidx(Rq, q * 8)];
    const bf16x8 qb1 = *(const bf16x8*)&qs[sidx(Rq, 32 + q * 8)];
    const ushortx8 v0 = *(const ushortx8*)&vs[sidx(Rq, q * 16)];
    const ushortx8 v1 = *(const ushortx8*)&vs[sidx(Rq, q * 16 + 8)];
#pragma unroll
    for (int j = 0; j < 8; j++) vtw[q * 16 + (q * 16 + j) * 24 + m] = v0[j];
#pragma unroll
    for (int j = 0; j < 8; j++) vtw[q * 16 + (q * 16 + 8 + j) * 24 + m] = v1[j];

    floatx4 s = (floatx4){0.f, 0.f, 0.f, 0.f};
    s = __builtin_amdgcn_mfma_f32_16x16x32_bf16(ka0, qb0, s, 0, 0, 0);
    s = __builtin_amdgcn_mfma_f32_16x16x32_bf16(ka1, qb1, s, 0, 0, 0);

    unsigned short pb0 = f2bu(__expf(s[0])), pb1 = f2bu(__expf(s[1]));
    unsigned short pb2 = f2bu(__expf(s[2])), pb3 = f2bu(__expf(s[3]));
    float asum = bu2f(pb0) + bu2f(pb1) + bu2f(pb2) + bu2f(pb3);
    asum += __shfl_xor(asum, 16, 64);
    asum += __shfl_xor(asum, 32, 64);

    unsigned int d0 = (unsigned int)pb0 | ((unsigned int)pb1 << 16);
    unsigned int d1 = (unsigned int)pb2 | ((unsigned int)pb3 << 16);
    const int s0l = m + 32 * (q & 1);
    unsigned int u0 = __shfl(d0, s0l, 64);
    unsigned int u1 = __shfl(d1, s0l, 64);
    unsigned int u2 = __shfl(d0, s0l + 16, 64);
    unsigned int u3 = __shfl(d1, s0l + 16, 64);
    union { uintx4 i; bf16x8 b; } pau;
    pau.i = (q < 2) ? (uintx4){u0, u1, u2, u3} : (uintx4){0u, 0u, 0u, 0u};
    const bf16x8 pa = pau.b;

#pragma unroll
    for (int cc = 0; cc < 4; cc++) {
      union { uintx4 i; bf16x8 b; } bvu;
      bvu.i = (uintx4){0u, 0u, 0u, 0u};
      if (q < 2) bvu.b = *(const bf16x8*)&vtw[cc * 16 + (cc * 16 + m) * 24 + q * 8];
      floatx4 y = (floatx4){0.f, 0.f, 0.f, 0.f};
      y = __builtin_amdgcn_mfma_f32_16x16x32_bf16(pa, bvu.b, y, 0, 0, 0);
      yout[cc] = y;
    }
    return asum;
  };

  auto pyr = [&](int l) {
    const int nOut = 256 >> l;
    for (int e = tid; e < nOut * 32; e += 512) {
      const int i = e >> 5, dp = (e & 31) * 2;
      const int ra = i << l, rb = ra + (1 << (l - 1));
      const int ia = sidx(ra, dp), ib = sidx(rb, dp);
      unsigned short q0 = f2bu(0.5f * (bu2f(qs[ia]) + bu2f(qs[ib])));
      unsigned short q1 = f2bu(0.5f * (bu2f(qs[ia + 1]) + bu2f(qs[ib + 1])));
      unsigned short k0 = f2bu(0.5f * (bu2f(ks[ia]) + bu2f(ks[ib])));
      unsigned short k1 = f2bu(0.5f * (bu2f(ks[ia + 1]) + bu2f(ks[ib + 1])));
      unsigned short v0 = f2bu(bu2f(vs[ia]) + bu2f(vs[ib]));
      unsigned short v1 = f2bu(bu2f(vs[ia + 1]) + bu2f(vs[ib + 1]));
      qs[ia] = q0; qs[ia + 1] = q1;
      ks[ia] = k0; ks[ia + 1] = k1;
      vs[ia] = v0; vs[ia + 1] = v1;
    }
  };

  auto emit = [&](int ro, int blk, const floatx4 yt[4], float a) {
    const size_t arow = base + ro + blk * 16;
    if (q == 0) aall[arow + m] = a;
#pragma unroll
    for (int cc = 0; cc < 4; cc++)
#pragma unroll
      for (int r = 0; r < 4; r++)
        yall[(arow + q * 4 + r) * 64 + cc * 16 + m] = __float2bfloat16(yt[cc][r]);
  };

  // level 4 (local 0): 16 blocks over 8 waves
  {
    floatx4 yt[4];
#pragma unroll
    for (int t = 0; t < 2; t++) {
      const int blk = w + t * 8;
      float a = attn_block(0, blk, true, yt);
      emit(7680, blk, yt, a);
    }
  }
  __syncthreads();
  pyr(1);
  __syncthreads();
  // level 5 (local 1): 8 blocks
  {
    floatx4 yt[4];
    float a = attn_block(1, w, true, yt);
    emit(7936, w, yt, a);
  }
  __syncthreads();
  pyr(2);
  __syncthreads();
  // level 6 (local 2): 4 blocks
  if (w < 4) {
    floatx4 yt[4];
    float a = attn_block(2, w, true, yt);
    emit(8064, w, yt, a);
  }
  __syncthreads();
  pyr(3);
  __syncthreads();
  // level 7 (local 3): 2 blocks
  if (w < 2) {
    floatx4 yt[4];
    float a = attn_block(3, w, true, yt);
    emit(8128, w, yt, a);
  }
}

// ---- fused03 (512 thr): interleaved attn/pyramid levels 0..3 + combine ----
__global__ __launch_bounds__(512, 1) void fused03_kernel(
    const unsigned short* __restrict__ qp, const unsigned short* __restrict__ kp,
    const unsigned short* __restrict__ vp, const unsigned short* __restrict__ yall,
    const float* __restrict__ aall, __hip_bfloat16* __restrict__ Ub) {
  __shared__ __align__(16) unsigned short qs[256 * 64];
  __shared__ __align__(16) unsigned short ks[256 * 64];
  __shared__ __align__(16) unsigned short vs[256 * 64];
  __shared__ unsigned short ylds[224 * 72];  // y1: 0-127, y2: 128-191, y3: 192-223
  __shared__ float alds[480];                // a1:0-127 a2:128-191 a3:192-223 a0:224-479
  __shared__ __align__(16) unsigned short vT[8][VT_SZ];

  const int tid = threadIdx.x;
  const int w = tid >> 6, lane = tid & 63;
  const int m = lane & 15, q = lane >> 4;
  const int c = blockIdx.x, bh = blockIdx.y;
  const size_t base = (size_t)bh * ROWS_PER_BH;
  const size_t g0 = (base + c * 256) * 64;

  unsigned short* vtw = vT[w];

  // stage (pre-swizzled global source, linear LDS dest): 4 issues/tensor
  {
    const int srow = tid >> 3;                    // 0..63
    const int sch = (tid & 7) ^ swzf(srow);
    const size_t gofs = (size_t)srow * 64 + sch * 8;
#pragma unroll
    for (int it = 0; it < 4; it++) {
      const size_t gi = g0 + (size_t)it * 4096 + gofs;
      g2lds16(qp + gi, &qs[it * 4096 + tid * 8]);
      g2lds16(kp + gi, &ks[it * 4096 + tid * 8]);
      g2lds16(vp + gi, &vs[it * 4096 + tid * 8]);
    }
  }
  __syncthreads();

  auto attn_block = [&](int level, int blk, bool flip, floatx4 yout[4]) -> float {
    const int kb = flip ? (blk ^ 1) : blk;
    const int Rq = (blk * 16 + m) << level;
    const int Rk = (kb * 16 + m) << level;
    const bf16x8 ka0 = *(const bf16x8*)&ks[sidx(Rk, q * 8)];
    const bf16x8 ka1 = *(const bf16x8*)&ks[sidx(Rk, 32 + q * 8)];
    const bf16x8 qb0 = *(const bf16x8*)&qs[sidx(Rq, q * 8)];
    const bf16x8 qb1 = *(const bf16x8*)&qs[sidx(Rq, 32 + q * 8)];
    const ushortx8 v0 = *(const ushortx8*)&vs[sidx(Rq, q * 16)];
    const ushortx8 v1 = *(const ushortx8*)&vs[sidx(Rq, q * 16 + 8)];
#pragma unroll
    for (int j = 0; j < 8; j++) vtw[q * 16 + (q * 16 + j) * 24 + m] = v0[j];
#pragma unroll
    for (int j = 0; j < 8; j++) vtw[q * 16 + (q * 16 + 8 + j) * 24 + m] = v1[j];

    floatx4 s = (floatx4){0.f, 0.f, 0.f, 0.f};
    s = __builtin_amdgcn_mfma_f32_16x16x32_bf16(ka0, qb0, s, 0, 0, 0);
    s = __builtin_amdgcn_mfma_f32_16x16x32_bf16(ka1, qb1, s, 0, 0, 0);

    unsigned short pb0 = f2bu(__expf(s[0])), pb1 = f2bu(__expf(s[1]));
    unsigned short pb2 = f2bu(__expf(s[2])), pb3 = f2bu(__expf(s[3]));
    float asum = bu2f(pb0) + bu2f(pb1) + bu2f(pb2) + bu2f(pb3);
    asum += __shfl_xor(asum, 16, 64);
    asum += __shfl_xor(asum, 32, 64);

    unsigned int d0 = (unsigned int)pb0 | ((unsigned int)pb1 << 16);
    unsigned int d1 = (unsigned int)pb2 | ((unsigned int)pb3 << 16);
    const int s0l = m + 32 * (q & 1);
    unsigned int u0 = __shfl(d0, s0l, 64);
    unsigned int u1 = __shfl(d1, s0l, 64);
    unsigned int u2 = __shfl(d0, s0l + 16, 64);
    unsigned int u3 = __shfl(d1, s0l + 16, 64);
    union { uintx4 i; bf16x8 b; } pau;
    pau.i = (q < 2) ? (uintx4){u0, u1, u2, u3} : (uintx4){0u, 0u, 0u, 0u};
    const bf16x8 pa = pau.b;

#pragma unroll
    for (int cc = 0; cc < 4; cc++) {
      union { uintx4 i; bf16x8 b; } bvu;
      bvu.i = (uintx4){0u, 0u, 0u, 0u};
      if (q < 2) bvu.b = *(const bf16x8*)&vtw[cc * 16 + (cc * 16 + m) * 24 + q * 8];
      floatx4 y = (floatx4){0.f, 0.f, 0.f, 0.f};
      y = __builtin_amdgcn_mfma_f32_16x16x32_bf16(pa, bvu.b, y, 0, 0, 0);
      yout[cc] = y;
    }
    return asum;
  };

  auto pyr = [&](int l) {
    const int nOut = 256 >> l;
    for (int e = tid; e < nOut * 32; e += 512) {
      const int i = e >> 5, dp = (e & 31) * 2;
      const int ra = i << l, rb = ra + (1 << (l - 1));
      const int ia = sidx(ra, dp), ib = sidx(rb, dp);
      unsigned short q0 = f2bu(0.5f * (bu2f(qs[ia]) + bu2f(qs[ib])));
      unsigned short q1 = f2bu(0.5f * (bu2f(qs[ia + 1]) + bu2f(qs[ib + 1])));
      unsigned short k0 = f2bu(0.5f * (bu2f(ks[ia]) + bu2f(ks[ib])));
      unsigned short k1 = f2bu(0.5f * (bu2f(ks[ia + 1]) + bu2f(ks[ib + 1])));
      unsigned short v0 = f2bu(bu2f(vs[ia]) + bu2f(vs[ib]));
      unsigned short v1 = f2bu(bu2f(vs[ia + 1]) + bu2f(vs[ib + 1]));
      qs[ia] = q0; qs[ia + 1] = q1;
      ks[ia] = k0; ks[ia + 1] = k1;
      vs[ia] = v0; vs[ia + 1] = v1;
    }
  };

  // ---- attn level 0 (16 blocks over 8 waves), y0 kept in registers
  floatx4 y0reg[2][4];
#pragma unroll
  for (int t = 0; t < 2; t++) {
    const int blk = w + t * 8;
    float a0 = attn_block(0, blk, false, y0reg[t]);
    if (q == 0) alds[224 + blk * 16 + m] = a0;
  }
  __syncthreads();

  // ---- levels 1..3: build, then attend (write y to ylds, a to alds)
  pyr(1);
  __syncthreads();
  {
    floatx4 yt[4];
    const int blk = w;                 // 8 blocks / 8 waves
    float a = attn_block(1, blk, true, yt);
    if (q == 0) alds[blk * 16 + m] = a;
#pragma unroll
    for (int cc = 0; cc < 4; cc++)
#pragma unroll
      for (int r = 0; r < 4; r++)
        ylds[(blk * 16 + q * 4 + r) * 72 + cc * 16 + m] = f2bu(yt[cc][r]);
  }
  __syncthreads();
  pyr(2);
  __syncthreads();
  if (w < 4) {
    floatx4 yt[4];
    const int blk = w;                 // 4 blocks on waves 0..3
    float a = attn_block(2, blk, true, yt);
    if (q == 0) alds[128 + blk * 16 + m] = a;
#pragma unroll
    for (int cc = 0; cc < 4; cc++)
#pragma unroll
      for (int r = 0; r < 4; r++)
        ylds[(128 + blk * 16 + q * 4 + r) * 72 + cc * 16 + m] = f2bu(yt[cc][r]);
  }
  __syncthreads();
  pyr(3);
  __syncthreads();
  if (w < 2) {
    floatx4 yt[4];
    const int blk = w;                 // 2 blocks on waves 0,1
    float a = attn_block(3, blk, true, yt);
    if (q == 0) alds[192 + blk * 16 + m] = a;
#pragma unroll
    for (int cc = 0; cc < 4; cc++)
#pragma unroll
      for (int r = 0; r < 4; r++)
        ylds[(192 + blk * 16 + q * 4 + r) * 72 + cc * 16 + m] = f2bu(yt[cc][r]);
  }
  __syncthreads();

  // ---- final combine: U = (y0 + y1 + y2 + y3 + ycoarse) / (sum a + eps)
  const int bO = bh >> 3, hO = bh & 7;
#pragma unroll
  for (int t = 0; t < 2; t++) {
    const int blk = w + t * 8;
    const int i4 = c * 16 + blk;
    const size_t r4 = base + 7680 + i4;
    const size_t r5 = base + 7936 + (i4 >> 1);
    const size_t r6 = base + 8064 + (i4 >> 2);
    const size_t r7 = base + 8128 + (i4 >> 3);
    const float acoarse = aall[r4] + aall[r5] + aall[r6] + aall[r7];

    float inv[4];
#pragma unroll
    for (int r = 0; r < 4; r++) {
      const int row = blk * 16 + q * 4 + r;
      const float atot = alds[224 + row] + alds[row >> 1] +
                         alds[128 + (row >> 2)] + alds[192 + (row >> 3)] +
                         acoarse + 1e-8f;
      inv[r] = 1.0f / atot;
    }

#pragma unroll
    for (int cc = 0; cc < 4; cc++) {
      const int col = cc * 16 + m;
      const float yc = bu2f(yall[r4 * 64 + col]) + bu2f(yall[r5 * 64 + col]) +
                       bu2f(yall[r6 * 64 + col]) + bu2f(yall[r7 * 64 + col]);
#pragma unroll
      for (int r = 0; r < 4; r++) {
        const int row = blk * 16 + q * 4 + r;
        const float num = y0reg[t][cc][r] + bu2f(ylds[(row >> 1) * 72 + col]) +
                          bu2f(ylds[(128 + (row >> 2)) * 72 + col]) +
                          bu2f(ylds[(192 + (row >> 3)) * 72 + col]) + yc;
        Ub[((size_t)bO * 4096 + c * 256 + row) * 512 + hO * 64 + col] =
            __float2bfloat16(num * inv[r]);
      }
    }
  }
}

// ---------------------------------------------------------------------------
extern "C" void kernel_launch(void* const* d_in, const int* in_sizes, int n_in,
                              void* d_out, int out_size, void* d_ws, size_t ws_size,
                              hipStream_t stream) {
  const float* x     = (const float*)d_in[0];  // [4,4096,1024]
  const float* w_qkv = (const float*)d_in[1];  // [1536,1024]
  const float* w_out = (const float*)d_in[2];  // [1024,512]
  const float* b_out = (const float*)d_in[3];  // [1024]
  float* out = (float*)d_out;

  char* ws = (char*)d_ws;
  __hip_bfloat16* xb    = (__hip_bfloat16*)(ws + 0);           // 33554432 B
  __hip_bfloat16* wqkvb = (__hip_bfloat16*)(ws + 33554432);    //  3145728 B
  __hip_bfloat16* wob   = (__hip_bfloat16*)(ws + 36700160);    //  1048576 B
  __hip_bfloat16* qp    = (__hip_bfloat16*)(ws + 37748736);    // 33423360 B
  __hip_bfloat16* kp    = (__hip_bfloat16*)(ws + 71172096);    // 33423360 B
  __hip_bfloat16* vp    = (__hip_bfloat16*)(ws + 104595456);   // 33423360 B
  __hip_bfloat16* yall  = (__hip_bfloat16*)(ws + 138018816);   // 33423360 B
  float* aall           = (float*)(ws + 171442176);            //  1044480 B
  __hip_bfloat16* Ub    = (__hip_bfloat16*)(ws + 172486656);   // 16777216 B

  // 1) converts (single launch, 8 elems/thread)
  f2b3_kernel<<<9216, 256, 0, stream>>>(x, w_qkv, w_out, xb, wqkvb, wob);

  // 2) qkv projection + level-0 scatter + level-4 emission (2 dispatches)
  gemm_qkv_kernel<<<dim3(64, 12), 256, 0, stream>>>(
      (const unsigned short*)xb, (const unsigned short*)wqkvb, qp, kp, vp, 0);
  gemm_qkv_kernel<<<dim3(64, 12), 256, 0, stream>>>(
      (const unsigned short*)xb, (const unsigned short*)wqkvb, qp, kp, vp, 8192);

  // 3) coarse levels 4..7: pyramid + attention fused, per bh
  coarse47_kernel<<<32, 512, 0, stream>>>(
      (const unsigned short*)qp, (const unsigned short*)kp,
      (const unsigned short*)vp, yall, aall);

  // 4) fused levels 0..3 pyramid + attn + final combine -> Ub
  fused03_kernel<<<dim3(16, 32), 512, 0, stream>>>(
      (const unsigned short*)qp, (const unsigned short*)kp,
      (const unsigned short*)vp, (const unsigned short*)yall, aall, Ub);

  // 5) out projection + bias
  gemm_out_kernel<<<dim3(128, 8), 256, 0, stream>>>(
      (const unsigned short*)Ub, (const unsigned short*)wob, b_out, out);
}

// Round 8
// 256.455 us; speedup vs baseline: 1.0570x; 1.0570x over previous
//
#include <hip/hip_runtime.h>
#include <hip/hip_bf16.h>

// ---------------------------------------------------------------------------
// HAttention1D: B=4 N=4096 DIM=1024 HEADS=8 DH=64 BSZ=16, 8 levels (0..7)
//  1) f2b3: x, w_qkv, w_out -> bf16 (single launch, 8 elems/thread)
//  2) gemm_qkv (128x128 MFMA): qkv = x@w_qkv^T; epilogue scatters level-0
//     AND emits levels 1..4 directly from f32 accumulators (in-lane sums +
//     shfl_xor) -> whole pyramid 0..4 materialized by the GEMM
//  3) coarse47 (per bh, 512 thr): stage level-4, build 5..7 + attn 4..7
//  4) fused03 (per (bh,256-row chunk), 512 thr, 2 blocks/CU): 30 independent
//     attn blocks (levels 0..3) reading global directly, ONE barrier, then
//     fused final combine -> Ub
//  5) gemm_out (128x128 MFMA): out = U @ w_out^T + b_out
// ---------------------------------------------------------------------------

typedef __bf16 bf16x8 __attribute__((ext_vector_type(8)));
typedef float floatx4 __attribute__((ext_vector_type(4)));
typedef unsigned short ushortx8 __attribute__((ext_vector_type(8)));
typedef unsigned int uintx4 __attribute__((ext_vector_type(4)));

#define ROWS_PER_BH 8160  // 4096+2048+1024+512+256+128+64+32

__device__ __forceinline__ void g2lds16(const void* g, void* l) {
  __builtin_amdgcn_global_load_lds(
      (const __attribute__((address_space(1))) void*)g,
      (__attribute__((address_space(3))) void*)l, 16, 0, 0);
}

__device__ __forceinline__ unsigned short f2bu(float x) {
  __hip_bfloat16 h = __float2bfloat16(x);
  return *(unsigned short*)&h;
}
__device__ __forceinline__ float bu2f(unsigned short u) {
  __hip_bfloat16 h = *(__hip_bfloat16*)&u;
  return __bfloat162float(h);
}

// ---- fp32 -> bf16 convert, all three tensors, 8 elems/thread --------------
__global__ __launch_bounds__(256) void f2b3_kernel(const float* __restrict__ x,
                                                   const float* __restrict__ wq,
                                                   const float* __restrict__ wo,
                                                   __hip_bfloat16* __restrict__ xb,
                                                   __hip_bfloat16* __restrict__ wqb,
                                                   __hip_bfloat16* __restrict__ wob) {
  int i0 = (blockIdx.x * 256 + threadIdx.x) * 8;
  const float* s;
  __hip_bfloat16* d;
  if (i0 < 16777216) {
    s = x + i0; d = xb + i0;
  } else if (i0 < 16777216 + 1572864) {
    s = wq + (i0 - 16777216); d = wqb + (i0 - 16777216);
  } else {
    s = wo + (i0 - 16777216 - 1572864); d = wob + (i0 - 16777216 - 1572864);
  }
  float4 v0 = *(const float4*)s;
  float4 v1 = *(const float4*)(s + 4);
  ushortx8 o;
  o[0] = f2bu(v0.x); o[1] = f2bu(v0.y); o[2] = f2bu(v0.z); o[3] = f2bu(v0.w);
  o[4] = f2bu(v1.x); o[5] = f2bu(v1.y); o[6] = f2bu(v1.z); o[7] = f2bu(v1.w);
  *(ushortx8*)d = o;
}

// ---- shared GEMM core: 128x128 tile, BK=64, XOR-swizzled LDS --------------
template <int K>
__device__ __forceinline__ void gemm_core(const unsigned short* __restrict__ A,
                                          const unsigned short* __restrict__ B,
                                          unsigned short* ldsA, unsigned short* ldsB,
                                          int tM, int tN, floatx4 acc[4][4]) {
  const int tid = threadIdx.x;
  const int lane = tid & 63, w = tid >> 6;
  const int wm = w >> 1, wn = w & 1;
  const int lr = lane >> 3;            // row-within-8 for staging
  const int gch = (lane & 7) ^ lr;     // XOR-swizzled global chunk
  const unsigned short* Ag = A + (size_t)(tM + w * 32 + lr) * K + gch * 8;
  const unsigned short* Bg = B + (size_t)(tN + w * 32 + lr) * K + gch * 8;
  unsigned short* lA = &ldsA[w * 2048 + lane * 8];
  unsigned short* lB = &ldsB[w * 2048 + lane * 8];

  const int rA = wm * 64 + (lane & 15);
  const int rB = wn * 64 + (lane & 15);
  const int quad = lane >> 4;
  const int sw = lane & 7;             // fragment row & 7

  for (int kt = 0; kt < K; kt += 64) {
    __syncthreads();
#pragma unroll
    for (int c = 0; c < 4; c++) {
      g2lds16(Ag + (size_t)(c * 8) * K + kt, lA + c * 512);
      g2lds16(Bg + (size_t)(c * 8) * K + kt, lB + c * 512);
    }
    __syncthreads();
#pragma unroll
    for (int kk = 0; kk < 2; kk++) {
      bf16x8 af[4], bv[4];
#pragma unroll
      for (int i = 0; i < 4; i++)
        af[i] = *(const bf16x8*)&ldsA[(rA + i * 16) * 64 + (((kk * 4 + quad) ^ sw) * 8)];
#pragma unroll
      for (int j = 0; j < 4; j++)
        bv[j] = *(const bf16x8*)&ldsB[(rB + j * 16) * 64 + (((kk * 4 + quad) ^ sw) * 8)];
#pragma unroll
      for (int i = 0; i < 4; i++)
#pragma unroll
        for (int j = 0; j < 4; j++)
          acc[i][j] = __builtin_amdgcn_mfma_f32_16x16x32_bf16(af[i], bv[j], acc[i][j], 0, 0, 0);
    }
  }
}

// pyramid level offsets within a bh row-block
__constant__ int LVLOFF[8] = {0, 4096, 6144, 7168, 7680, 7936, 8064, 8128};

// ---- GEMM1: qkv = x[16384,1024] @ w_qkv[1536,1024]^T ----------------------
// epilogue: scatter level-0 + emit levels 1..4 from f32 accumulators.
// fragment = 16 consecutive rows: lvl1 = in-lane pair sums, lvl2 = in-lane
// quad sum, lvl3 = +shfl_xor16, lvl4 = +shfl_xor32.
__global__ __launch_bounds__(256) void gemm_qkv_kernel(
    const unsigned short* __restrict__ A,   // xb [16384,1024] bf16
    const unsigned short* __restrict__ B,   // wqkvb [1536,1024] bf16
    __hip_bfloat16* __restrict__ qp, __hip_bfloat16* __restrict__ kp,
    __hip_bfloat16* __restrict__ vp) {
  __shared__ unsigned short ldsA[128 * 64];
  __shared__ unsigned short ldsB[128 * 64];
  const int lane = threadIdx.x & 63, w = threadIdx.x >> 6;
  const int wm = w >> 1, wn = w & 1;
  const int tM = blockIdx.x * 128, tN = blockIdx.y * 128;

  floatx4 acc[4][4];
#pragma unroll
  for (int i = 0; i < 4; i++)
#pragma unroll
    for (int j = 0; j < 4; j++) acc[i][j] = (floatx4){0.f, 0.f, 0.f, 0.f};

  gemm_core<1024>(A, B, ldsA, ldsB, tM, tN, acc);

  // epilogue: C/D layout col=lane&15, row=(lane>>4)*4+r  [verified m89]
  const int quad = lane >> 4, m15 = lane & 15;
#pragma unroll
  for (int i = 0; i < 4; i++) {
#pragma unroll
    for (int j = 0; j < 4; j++) {
      const int c = tN + wn * 64 + j * 16 + m15;
      const int tensor = c >> 9;         // 0=q 1=k 2=v
      const int rem = c & 511;
      const int h = rem >> 6, d = rem & 63;
      __hip_bfloat16* dstbuf = (tensor == 0) ? qp : ((tensor == 1) ? kp : vp);
      const float scale = (tensor == 0) ? 0.125f : 1.0f;  // DH^-0.5
#pragma unroll
      for (int r = 0; r < 4; r++) {
        const int m = tM + wm * 64 + i * 16 + quad * 4 + r;
        const int b = m >> 12, n = m & 4095;
        size_t dst = ((size_t)(b * 8 + h) * ROWS_PER_BH + n) * 64 + d;
        dstbuf[dst] = __float2bfloat16(acc[i][j][r] * scale);
      }
      // levels 1..4 from f32 accs (v sums, q/k means; q keeps 0.125 fold)
      const float s2a = acc[i][j][0] + acc[i][j][1];
      const float s2b = acc[i][j][2] + acc[i][j][3];
      const float s4v = s2a + s2b;
      const float s8v = s4v + __shfl_xor(s4v, 16, 64);
      const float s16v = s8v + __shfl_xor(s8v, 32, 64);
      const int mg = tM + wm * 64 + i * 16;     // 16-row group start
      const int b = mg >> 12, nb = mg & 4095;
      const size_t rb = (size_t)(b * 8 + h) * ROWS_PER_BH;
      const bool isv = (tensor == 2);
      // level 1: rows (nb>>1)+quad*2 (+0,+1)
      {
        const float dv = isv ? 1.f : 0.5f;
        const int n1 = (nb >> 1) + quad * 2;
        dstbuf[(rb + 4096 + n1) * 64 + d] = __float2bfloat16(s2a * dv * scale);
        dstbuf[(rb + 4096 + n1 + 1) * 64 + d] = __float2bfloat16(s2b * dv * scale);
      }
      // level 2: row (nb>>2)+quad
      {
        const float dv = isv ? 1.f : 0.25f;
        dstbuf[(rb + 6144 + (nb >> 2) + quad) * 64 + d] =
            __float2bfloat16(s4v * dv * scale);
      }
      // level 3: row (nb>>3)+(quad>>1), emit from quads 0,2
      if ((quad & 1) == 0) {
        const float dv = isv ? 1.f : 0.125f;
        dstbuf[(rb + 7168 + (nb >> 3) + (quad >> 1)) * 64 + d] =
            __float2bfloat16(s8v * dv * scale);
      }
      // level 4: row nb>>4, emit from quad 0
      if (quad == 0) {
        const float dv = isv ? 1.f : 0.0625f;
        dstbuf[(rb + 7680 + (nb >> 4)) * 64 + d] =
            __float2bfloat16(s16v * dv * scale);
      }
    }
  }
}

// ---- GEMM2: out = U[16384,512] @ w_out[1024,512]^T + b_out ----------------
__global__ __launch_bounds__(256) void gemm_out_kernel(
    const unsigned short* __restrict__ A,   // Ub [16384,512] bf16
    const unsigned short* __restrict__ B,   // wob [1024,512] bf16
    const float* __restrict__ bias, float* __restrict__ out) {
  __shared__ unsigned short ldsA[128 * 64];
  __shared__ unsigned short ldsB[128 * 64];
  const int lane = threadIdx.x & 63, w = threadIdx.x >> 6;
  const int wm = w >> 1, wn = w & 1;
  const int tM = blockIdx.x * 128, tN = blockIdx.y * 128;

  floatx4 acc[4][4];
#pragma unroll
  for (int i = 0; i < 4; i++)
#pragma unroll
    for (int j = 0; j < 4; j++) acc[i][j] = (floatx4){0.f, 0.f, 0.f, 0.f};

  gemm_core<512>(A, B, ldsA, ldsB, tM, tN, acc);

  const int quad = lane >> 4;
#pragma unroll
  for (int i = 0; i < 4; i++) {
#pragma unroll
    for (int j = 0; j < 4; j++) {
      const int c = tN + wn * 64 + j * 16 + (lane & 15);
      const float bb = bias[c];
#pragma unroll
      for (int r = 0; r < 4; r++) {
        const int m = tM + wm * 64 + i * 16 + quad * 4 + r;
        out[(size_t)m * 1024 + c] = acc[i][j][r] + bb;
      }
    }
  }
}

// swizzle class: full 8-way spread even for rows strided by 2^l (l<=3)
__device__ __forceinline__ int swzf(int r) { return (r ^ (r >> 3)) & 7; }
__device__ __forceinline__ int sidx(int r, int d) {
  return r * 64 + (((d >> 3) ^ swzf(r)) << 3) + (d & 7);
}
// vT: element (d, vrow) at (d>>4)*16 + d*24 + vrow (per-q 16-short pad)
#define VT_SZ 1600

// ---- coarse47: per bh (512 thr): levels 4..7 attn+pyramid in LDS ----------
__global__ __launch_bounds__(512, 1) void coarse47_kernel(
    const unsigned short* __restrict__ qp, const unsigned short* __restrict__ kp,
    const unsigned short* __restrict__ vp, __hip_bfloat16* __restrict__ yall,
    float* __restrict__ aall) {
  __shared__ __align__(16) unsigned short qs[256 * 64];
  __shared__ __align__(16) unsigned short ks[256 * 64];
  __shared__ __align__(16) unsigned short vs[256 * 64];
  __shared__ __align__(16) unsigned short vT[8][VT_SZ];

  const int tid = threadIdx.x;
  const int w = tid >> 6, lane = tid & 63;
  const int m = lane & 15, q = lane >> 4;
  const int bh = blockIdx.x;
  const size_t base = (size_t)bh * ROWS_PER_BH;
  const size_t g0 = (base + 7680) * 64;

  unsigned short* vtw = vT[w];

  {
    const int srow = tid >> 3;                    // 0..63
    const int sch = (tid & 7) ^ swzf(srow);
    const size_t gofs = (size_t)srow * 64 + sch * 8;
#pragma unroll
    for (int it = 0; it < 4; it++) {
      const size_t gi = g0 + (size_t)it * 4096 + gofs;
      g2lds16(qp + gi, &qs[it * 4096 + tid * 8]);
      g2lds16(kp + gi, &ks[it * 4096 + tid * 8]);
      g2lds16(vp + gi, &vs[it * 4096 + tid * 8]);
    }
  }
  __syncthreads();

  auto attn_block = [&](int level, int blk, floatx4 yout[4]) -> float {
    const int kb = blk ^ 1;
    const int Rq = (blk * 16 + m) << level;
    const int Rk = (kb * 16 + m) << level;
    const bf16x8 ka0 = *(const bf16x8*)&ks[sidx(Rk, q * 8)];
    const bf16x8 ka1 = *(const bf16x8*)&ks[sidx(Rk, 32 + q * 8)];
    const bf16x8 qb0 = *(const bf16x8*)&qs[sidx(Rq, q * 8)];
    const bf16x8 qb1 = *(const bf16x8*)&qs[sidx(Rq, 32 + q * 8)];
    const ushortx8 v0 = *(const ushortx8*)&vs[sidx(Rq, q * 16)];
    const ushortx8 v1 = *(const ushortx8*)&vs[sidx(Rq, q * 16 + 8)];
#pragma unroll
    for (int j = 0; j < 8; j++) vtw[q * 16 + (q * 16 + j) * 24 + m] = v0[j];
#pragma unroll
    for (int j = 0; j < 8; j++) vtw[q * 16 + (q * 16 + 8 + j) * 24 + m] = v1[j];

    floatx4 s = (floatx4){0.f, 0.f, 0.f, 0.f};
    s = __builtin_amdgcn_mfma_f32_16x16x32_bf16(ka0, qb0, s, 0, 0, 0);
    s = __builtin_amdgcn_mfma_f32_16x16x32_bf16(ka1, qb1, s, 0, 0, 0);

    unsigned short pb0 = f2bu(__expf(s[0])), pb1 = f2bu(__expf(s[1]));
    unsigned short pb2 = f2bu(__expf(s[2])), pb3 = f2bu(__expf(s[3]));
    float asum = bu2f(pb0) + bu2f(pb1) + bu2f(pb2) + bu2f(pb3);
    asum += __shfl_xor(asum, 16, 64);
    asum += __shfl_xor(asum, 32, 64);

    unsigned int d0 = (unsigned int)pb0 | ((unsigned int)pb1 << 16);
    unsigned int d1 = (unsigned int)pb2 | ((unsigned int)pb3 << 16);
    const int s0l = m + 32 * (q & 1);
    unsigned int u0 = __shfl(d0, s0l, 64);
    unsigned int u1 = __shfl(d1, s0l, 64);
    unsigned int u2 = __shfl(d0, s0l + 16, 64);
    unsigned int u3 = __shfl(d1, s0l + 16, 64);
    union { uintx4 i; bf16x8 b; } pau;
    pau.i = (q < 2) ? (uintx4){u0, u1, u2, u3} : (uintx4){0u, 0u, 0u, 0u};
    const bf16x8 pa = pau.b;

#pragma unroll
    for (int cc = 0; cc < 4; cc++) {
      union { uintx4 i; bf16x8 b; } bvu;
      bvu.i = (uintx4){0u, 0u, 0u, 0u};
      if (q < 2) bvu.b = *(const bf16x8*)&vtw[cc * 16 + (cc * 16 + m) * 24 + q * 8];
      floatx4 y = (floatx4){0.f, 0.f, 0.f, 0.f};
      y = __builtin_amdgcn_mfma_f32_16x16x32_bf16(pa, bvu.b, y, 0, 0, 0);
      yout[cc] = y;
    }
    return asum;
  };

  auto pyr = [&](int l) {
    const int nOut = 256 >> l;
    for (int e = tid; e < nOut * 32; e += 512) {
      const int i = e >> 5, dp = (e & 31) * 2;
      const int ra = i << l, rb2 = ra + (1 << (l - 1));
      const int ia = sidx(ra, dp), ib = sidx(rb2, dp);
      unsigned short q0 = f2bu(0.5f * (bu2f(qs[ia]) + bu2f(qs[ib])));
      unsigned short q1 = f2bu(0.5f * (bu2f(qs[ia + 1]) + bu2f(qs[ib + 1])));
      unsigned short k0 = f2bu(0.5f * (bu2f(ks[ia]) + bu2f(ks[ib])));
      unsigned short k1 = f2bu(0.5f * (bu2f(ks[ia + 1]) + bu2f(ks[ib + 1])));
      unsigned short v0 = f2bu(bu2f(vs[ia]) + bu2f(vs[ib]));
      unsigned short v1 = f2bu(bu2f(vs[ia + 1]) + bu2f(vs[ib + 1]));
      qs[ia] = q0; qs[ia + 1] = q1;
      ks[ia] = k0; ks[ia + 1] = k1;
      vs[ia] = v0; vs[ia + 1] = v1;
    }
  };

  auto emit = [&](int ro, int blk, const floatx4 yt[4], float a) {
    const size_t arow = base + ro + blk * 16;
    if (q == 0) aall[arow + m] = a;
#pragma unroll
    for (int cc = 0; cc < 4; cc++)
#pragma unroll
      for (int r = 0; r < 4; r++)
        yall[(arow + q * 4 + r) * 64 + cc * 16 + m] = __float2bfloat16(yt[cc][r]);
  };

  // level 4 (local 0): 16 blocks over 8 waves
  {
    floatx4 yt[4];
#pragma unroll
    for (int t = 0; t < 2; t++) {
      const int blk = w + t * 8;
      float a = attn_block(0, blk, yt);
      emit(7680, blk, yt, a);
    }
  }
  __syncthreads();
  pyr(1);
  __syncthreads();
  {
    floatx4 yt[4];
    float a = attn_block(1, w, yt);
    emit(7936, w, yt, a);
  }
  __syncthreads();
  pyr(2);
  __syncthreads();
  if (w < 4) {
    floatx4 yt[4];
    float a = attn_block(2, w, yt);
    emit(8064, w, yt, a);
  }
  __syncthreads();
  pyr(3);
  __syncthreads();
  if (w < 2) {
    floatx4 yt[4];
    float a = attn_block(3, w, yt);
    emit(8128, w, yt, a);
  }
}

// ---- fused03 (512 thr, 2 blocks/CU): 30 independent attn blocks (lvl 0..3,
// global reads from the pre-built pyramid) + ONE barrier + fused combine ----
__global__ __launch_bounds__(512, 4) void fused03_kernel(
    const unsigned short* __restrict__ qp, const unsigned short* __restrict__ kp,
    const unsigned short* __restrict__ vp, const unsigned short* __restrict__ yall,
    const float* __restrict__ aall, __hip_bfloat16* __restrict__ Ub) {
  __shared__ unsigned short ylds[224 * 72];  // y1: 0-127, y2: 128-191, y3: 192-223
  __shared__ float alds[480];                // a1:0-127 a2:128-191 a3:192-223 a0:224-479
  __shared__ __align__(16) unsigned short vT[8][VT_SZ];

  const int tid = threadIdx.x;
  const int w = tid >> 6, lane = tid & 63;
  const int m = lane & 15, q = lane >> 4;
  const int c = blockIdx.x, bh = blockIdx.y;
  const size_t base = (size_t)bh * ROWS_PER_BH;

  unsigned short* vtw = vT[w];

  // attn block with direct global fragment loads (round-3-verified pattern)
  auto attn_g = [&](size_t qb, size_t kb, floatx4 yout[4]) -> float {
    const bf16x8 ka0 = *(const bf16x8*)(kp + kb + m * 64 + q * 8);
    const bf16x8 ka1 = *(const bf16x8*)(kp + kb + m * 64 + 32 + q * 8);
    const bf16x8 qv0 = *(const bf16x8*)(qp + qb + m * 64 + q * 8);
    const bf16x8 qv1 = *(const bf16x8*)(qp + qb + m * 64 + 32 + q * 8);
    const ushortx8 v0 = *(const ushortx8*)(vp + qb + m * 64 + q * 16);
    const ushortx8 v1 = *(const ushortx8*)(vp + qb + m * 64 + q * 16 + 8);
#pragma unroll
    for (int j = 0; j < 8; j++) vtw[q * 16 + (q * 16 + j) * 24 + m] = v0[j];
#pragma unroll
    for (int j = 0; j < 8; j++) vtw[q * 16 + (q * 16 + 8 + j) * 24 + m] = v1[j];

    floatx4 s = (floatx4){0.f, 0.f, 0.f, 0.f};
    s = __builtin_amdgcn_mfma_f32_16x16x32_bf16(ka0, qv0, s, 0, 0, 0);
    s = __builtin_amdgcn_mfma_f32_16x16x32_bf16(ka1, qv1, s, 0, 0, 0);

    unsigned short pb0 = f2bu(__expf(s[0])), pb1 = f2bu(__expf(s[1]));
    unsigned short pb2 = f2bu(__expf(s[2])), pb3 = f2bu(__expf(s[3]));
    float asum = bu2f(pb0) + bu2f(pb1) + bu2f(pb2) + bu2f(pb3);
    asum += __shfl_xor(asum, 16, 64);
    asum += __shfl_xor(asum, 32, 64);

    unsigned int d0 = (unsigned int)pb0 | ((unsigned int)pb1 << 16);
    unsigned int d1 = (unsigned int)pb2 | ((unsigned int)pb3 << 16);
    const int s0l = m + 32 * (q & 1);
    unsigned int u0 = __shfl(d0, s0l, 64);
    unsigned int u1 = __shfl(d1, s0l, 64);
    unsigned int u2 = __shfl(d0, s0l + 16, 64);
    unsigned int u3 = __shfl(d1, s0l + 16, 64);
    union { uintx4 i; bf16x8 b; } pau;
    pau.i = (q < 2) ? (uintx4){u0, u1, u2, u3} : (uintx4){0u, 0u, 0u, 0u};
    const bf16x8 pa = pau.b;

#pragma unroll
    for (int cc = 0; cc < 4; cc++) {
      union { uintx4 i; bf16x8 b; } bvu;
      bvu.i = (uintx4){0u, 0u, 0u, 0u};
      if (q < 2) bvu.b = *(const bf16x8*)&vtw[cc * 16 + (cc * 16 + m) * 24 + q * 8];
      floatx4 y = (floatx4){0.f, 0.f, 0.f, 0.f};
      y = __builtin_amdgcn_mfma_f32_16x16x32_bf16(pa, bvu.b, y, 0, 0, 0);
      yout[cc] = y;
    }
    return asum;
  };

  // global row base for (level, chunk-local blk); k flipped for level>0
  auto lvbase = [&](int l, int blk) -> size_t {
    return (base + LVLOFF[l] + c * (256 >> l) + blk * 16) * 64;
  };

  // ---- level 0: blocks w, w+8 (y0 in regs, no k-flip)
  floatx4 y0reg[2][4];
#pragma unroll
  for (int t = 0; t < 2; t++) {
    const int blk = w + t * 8;
    const size_t qb = lvbase(0, blk);
    float a0 = attn_g(qb, qb, y0reg[t]);
    if (q == 0) alds[224 + blk * 16 + m] = a0;
  }
  // ---- level 1: block w (8 waves, 8 blocks)
  {
    floatx4 yt[4];
    float a = attn_g(lvbase(1, w), lvbase(1, w ^ 1), yt);
    if (q == 0) alds[w * 16 + m] = a;
#pragma unroll
    for (int cc = 0; cc < 4; cc++)
#pragma unroll
      for (int r = 0; r < 4; r++)
        ylds[(w * 16 + q * 4 + r) * 72 + cc * 16 + m] = f2bu(yt[cc][r]);
  }
  // ---- level 2: waves 0..3; level 3: waves 4,5
  if (w < 4) {
    floatx4 yt[4];
    float a = attn_g(lvbase(2, w), lvbase(2, w ^ 1), yt);
    if (q == 0) alds[128 + w * 16 + m] = a;
#pragma unroll
    for (int cc = 0; cc < 4; cc++)
#pragma unroll
      for (int r = 0; r < 4; r++)
        ylds[(128 + w * 16 + q * 4 + r) * 72 + cc * 16 + m] = f2bu(yt[cc][r]);
  } else if (w < 6) {
    floatx4 yt[4];
    const int blk = w - 4;
    float a = attn_g(lvbase(3, blk), lvbase(3, blk ^ 1), yt);
    if (q == 0) alds[192 + blk * 16 + m] = a;
#pragma unroll
    for (int cc = 0; cc < 4; cc++)
#pragma unroll
      for (int r = 0; r < 4; r++)
        ylds[(192 + blk * 16 + q * 4 + r) * 72 + cc * 16 + m] = f2bu(yt[cc][r]);
  }
  __syncthreads();

  // ---- final combine: U = (y0 + y1 + y2 + y3 + ycoarse) / (sum a + eps)
  const int bO = bh >> 3, hO = bh & 7;
#pragma unroll
  for (int t = 0; t < 2; t++) {
    const int blk = w + t * 8;
    const int i4 = c * 16 + blk;
    const size_t r4 = base + 7680 + i4;
    const size_t r5 = base + 7936 + (i4 >> 1);
    const size_t r6 = base + 8064 + (i4 >> 2);
    const size_t r7 = base + 8128 + (i4 >> 3);
    const float acoarse = aall[r4] + aall[r5] + aall[r6] + aall[r7];

    float inv[4];
#pragma unroll
    for (int r = 0; r < 4; r++) {
      const int row = blk * 16 + q * 4 + r;
      const float atot = alds[224 + row] + alds[row >> 1] +
                         alds[128 + (row >> 2)] + alds[192 + (row >> 3)] +
                         acoarse + 1e-8f;
      inv[r] = 1.0f / atot;
    }

#pragma unroll
    for (int cc = 0; cc < 4; cc++) {
      const int col = cc * 16 + m;
      const float yc = bu2f(yall[r4 * 64 + col]) + bu2f(yall[r5 * 64 + col]) +
                       bu2f(yall[r6 * 64 + col]) + bu2f(yall[r7 * 64 + col]);
#pragma unroll
      for (int r = 0; r < 4; r++) {
        const int row = blk * 16 + q * 4 + r;
        const float num = y0reg[t][cc][r] + bu2f(ylds[(row >> 1) * 72 + col]) +
                          bu2f(ylds[(128 + (row >> 2)) * 72 + col]) +
                          bu2f(ylds[(192 + (row >> 3)) * 72 + col]) + yc;
        Ub[((size_t)bO * 4096 + c * 256 + row) * 512 + hO * 64 + col] =
            __float2bfloat16(num * inv[r]);
      }
    }
  }
}

// ---------------------------------------------------------------------------
extern "C" void kernel_launch(void* const* d_in, const int* in_sizes, int n_in,
                              void* d_out, int out_size, void* d_ws, size_t ws_size,
                              hipStream_t stream) {
  const float* x     = (const float*)d_in[0];  // [4,4096,1024]
  const float* w_qkv = (const float*)d_in[1];  // [1536,1024]
  const float* w_out = (const float*)d_in[2];  // [1024,512]
  const float* b_out = (const float*)d_in[3];  // [1024]
  float* out = (float*)d_out;

  char* ws = (char*)d_ws;
  __hip_bfloat16* xb    = (__hip_bfloat16*)(ws + 0);           // 33554432 B
  __hip_bfloat16* wqkvb = (__hip_bfloat16*)(ws + 33554432);    //  3145728 B
  __hip_bfloat16* wob   = (__hip_bfloat16*)(ws + 36700160);    //  1048576 B
  __hip_bfloat16* qp    = (__hip_bfloat16*)(ws + 37748736);    // 33423360 B
  __hip_bfloat16* kp    = (__hip_bfloat16*)(ws + 71172096);    // 33423360 B
  __hip_bfloat16* vp    = (__hip_bfloat16*)(ws + 104595456);   // 33423360 B
  __hip_bfloat16* yall  = (__hip_bfloat16*)(ws + 138018816);   // 33423360 B
  float* aall           = (float*)(ws + 171442176);            //  1044480 B
  __hip_bfloat16* Ub    = (__hip_bfloat16*)(ws + 172486656);   // 16777216 B

  // 1) converts (single launch, 8 elems/thread)
  f2b3_kernel<<<9216, 256, 0, stream>>>(x, w_qkv, w_out, xb, wqkvb, wob);

  // 2) qkv projection + pyramid levels 0..4 emission (single dispatch)
  gemm_qkv_kernel<<<dim3(128, 12), 256, 0, stream>>>(
      (const unsigned short*)xb, (const unsigned short*)wqkvb, qp, kp, vp);

  // 3) coarse levels 4..7: pyramid + attention fused, per bh
  coarse47_kernel<<<32, 512, 0, stream>>>(
      (const unsigned short*)qp, (const unsigned short*)kp,
      (const unsigned short*)vp, yall, aall);

  // 4) fused levels 0..3 attn + final combine -> Ub (no pyramid, 1 barrier)
  fused03_kernel<<<dim3(16, 32), 512, 0, stream>>>(
      (const unsigned short*)qp, (const unsigned short*)kp,
      (const unsigned short*)vp, (const unsigned short*)yall, aall, Ub);

  // 5) out projection + bias
  gemm_out_kernel<<<dim3(128, 8), 256, 0, stream>>>(
      (const unsigned short*)Ub, (const unsigned short*)wob, b_out, out);
}